// Round 1
// baseline (1618.795 us; speedup 1.0000x reference)
//
#include <hip/hip_runtime.h>

#define N_GENE 4762
#define N_CELL 847
#define NEDGE  200000
#define D      256

// ---- workspace layout (floats) ----
// deg/norm arrays are converted in-place deg -> rsqrt(max(deg,1))
#define A_DEG_G_OUT 0                         // [4762]  g2c_src histogram (genes)
#define A_DEG_C_IN  (A_DEG_G_OUT + N_GENE)    // [847]   g2c_dst histogram (cells)
#define A_DEG_C_OUT (A_DEG_C_IN + N_CELL)     // [847]   c2g_src histogram (cells)
#define A_DEG_G_IN  (A_DEG_C_OUT + N_CELL)    // [4762]  c2g_dst histogram (genes)
#define A_AGG_CELL  (A_DEG_G_IN + N_GENE)     // [847*256]
#define A_AGG_GENE  (A_AGG_CELL + N_CELL * D) // [4762*256]
#define A_SG        (A_AGG_GENE + N_GENE * D) // [4762]
#define A_SC        (A_SG + N_GENE)           // [847]
#define WS_ZERO_N   A_SG                      // zero everything before sg/sc

__global__ void k_zero(float* p, int n) {
    int i = blockIdx.x * blockDim.x + threadIdx.x;
    int stride = gridDim.x * blockDim.x;
    for (; i < n; i += stride) p[i] = 0.0f;
}

__global__ void k_deg(const int* __restrict__ g2c_src, const int* __restrict__ g2c_dst,
                      const int* __restrict__ c2g_src, const int* __restrict__ c2g_dst,
                      float* __restrict__ ws) {
    int i = blockIdx.x * blockDim.x + threadIdx.x;
    if (i < NEDGE) {
        atomicAdd(&ws[A_DEG_G_OUT + g2c_src[i]], 1.0f);
        atomicAdd(&ws[A_DEG_C_IN  + g2c_dst[i]], 1.0f);
        atomicAdd(&ws[A_DEG_C_OUT + c2g_src[i]], 1.0f);
        atomicAdd(&ws[A_DEG_G_IN  + c2g_dst[i]], 1.0f);
    }
}

// deg -> rsqrt(max(deg,1)) in place over all 4 arrays
__global__ void k_norm(float* __restrict__ ws, int n) {
    int i = blockIdx.x * blockDim.x + threadIdx.x;
    if (i < n) ws[i] = rsqrtf(fmaxf(ws[i], 1.0f));
}

// one wave per edge: agg[dst] += emb[src] * norm[src]
__global__ void k_agg(const float4* __restrict__ emb4, const int* __restrict__ src,
                      const int* __restrict__ dst, const float* __restrict__ norm,
                      float* __restrict__ agg) {
    int e = blockIdx.x * (blockDim.x >> 6) + (threadIdx.x >> 6);
    int lane = threadIdx.x & 63;
    if (e < NEDGE) {
        int s = src[e], d = dst[e];
        float sc = norm[s];
        float4 v = emb4[s * (D / 4) + lane];
        float* p = agg + d * D + lane * 4;
        atomicAdd(p + 0, v.x * sc);
        atomicAdd(p + 1, v.y * sc);
        atomicAdd(p + 2, v.z * sc);
        atomicAdd(p + 3, v.w * sc);
    }
}

// H = relu((X * norm_row) @ W + b), X:[M,256], W:[256,256], H:[M,256]
__global__ __launch_bounds__(256) void k_gemm_relu(
        const float* __restrict__ X, const float* __restrict__ normd,
        const float* __restrict__ W, const float* __restrict__ b,
        float* __restrict__ H, int M) {
    const int BM = 64, BN = 64, BK = 32;
    __shared__ float As[BK][BM + 1];
    __shared__ float Bs[BK][BN];
    int bm = blockIdx.y * BM, bn = blockIdx.x * BN;
    int t = threadIdx.x;
    int tx = t & 15, ty = t >> 4;
    float acc[4][4] = {};
    for (int k0 = 0; k0 < D; k0 += BK) {
        // A tile: 64 rows x 32 k, transposed into As[k][m], scaled by row norm
        {
            int m = t >> 3;
            int k4 = (t & 7) * 4;
            #pragma unroll
            for (int mm = 0; mm < BM; mm += 32) {
                int row = bm + m + mm;
                float4 v = make_float4(0.f, 0.f, 0.f, 0.f);
                float s = 0.f;
                if (row < M) {
                    v = *(const float4*)&X[row * D + k0 + k4];
                    s = normd[row];
                }
                As[k4 + 0][m + mm] = v.x * s;
                As[k4 + 1][m + mm] = v.y * s;
                As[k4 + 2][m + mm] = v.z * s;
                As[k4 + 3][m + mm] = v.w * s;
            }
        }
        // B tile: 32 k x 64 cols, direct layout
        {
            int k = t >> 4;
            int c4 = (t & 15) * 4;
            #pragma unroll
            for (int kk = 0; kk < BK; kk += 16) {
                *(float4*)&Bs[k + kk][c4] = *(const float4*)&W[(k0 + k + kk) * D + bn + c4];
            }
        }
        __syncthreads();
        #pragma unroll
        for (int k = 0; k < BK; k++) {
            float ra[4], rb[4];
            #pragma unroll
            for (int i = 0; i < 4; i++) ra[i] = As[k][ty * 4 + i];
            #pragma unroll
            for (int j = 0; j < 4; j++) rb[j] = Bs[k][tx * 4 + j];
            #pragma unroll
            for (int i = 0; i < 4; i++)
                #pragma unroll
                for (int j = 0; j < 4; j++) acc[i][j] += ra[i] * rb[j];
        }
        __syncthreads();
    }
    #pragma unroll
    for (int i = 0; i < 4; i++) {
        int row = bm + ty * 4 + i;
        if (row < M) {
            #pragma unroll
            for (int j = 0; j < 4; j++) {
                int col = bn + tx * 4 + j;
                H[row * D + col] = fmaxf(acc[i][j] + b[col], 0.0f);
            }
        }
    }
}

// out[r] = dot(H[r,:], wp[0:256]) — one wave per row
__global__ void k_rowdot(const float* __restrict__ H, const float* __restrict__ wp,
                         float* __restrict__ out, int M) {
    int r = blockIdx.x * (blockDim.x >> 6) + (threadIdx.x >> 6);
    int lane = threadIdx.x & 63;
    if (r < M) {
        float4 h = *(const float4*)&H[r * D + lane * 4];
        float4 w = *(const float4*)&wp[lane * 4];
        float s = h.x * w.x + h.y * w.y + h.z * w.z + h.w * w.w;
        #pragma unroll
        for (int o = 32; o > 0; o >>= 1) s += __shfl_down(s, o);
        if (lane == 0) out[r] = s;
    }
}

__global__ void k_score(const int* __restrict__ dsrc, const int* __restrict__ ddst,
                        const float* __restrict__ sg, const float* __restrict__ sc,
                        const float* __restrict__ bp, float* __restrict__ out) {
    int i = blockIdx.x * blockDim.x + threadIdx.x;
    if (i < NEDGE) out[i] = sg[dsrc[i]] + sc[ddst[i]] + bp[0];
}

extern "C" void kernel_launch(void* const* d_in, const int* in_sizes, int n_in,
                              void* d_out, int out_size, void* d_ws, size_t ws_size,
                              hipStream_t stream) {
    const float* gene_emb = (const float*)d_in[0];
    const float* cell_emb = (const float*)d_in[1];
    const float* W_g2c    = (const float*)d_in[2];
    const float* b_g2c    = (const float*)d_in[3];
    const float* W_c2g    = (const float*)d_in[4];
    const float* b_c2g    = (const float*)d_in[5];
    const float* Wp       = (const float*)d_in[6];
    const float* bp       = (const float*)d_in[7];
    const int* g2c_src = (const int*)d_in[8];
    const int* g2c_dst = (const int*)d_in[9];
    const int* c2g_src = (const int*)d_in[10];
    const int* c2g_dst = (const int*)d_in[11];
    const int* dec_src = (const int*)d_in[12];
    const int* dec_dst = (const int*)d_in[13];

    float* ws  = (float*)d_ws;
    float* out = (float*)d_out;
    float* out_score = out;                      // [200000]
    float* out_hgene = out + NEDGE;              // [4762*256]
    float* out_hcell = out + NEDGE + N_GENE * D; // [847*256]

    // 1. zero deg + agg regions of ws (re-poisoned 0xAA before every launch)
    k_zero<<<2048, 256, 0, stream>>>(ws, WS_ZERO_N);
    // 2. degrees
    k_deg<<<(NEDGE + 255) / 256, 256, 0, stream>>>(g2c_src, g2c_dst, c2g_src, c2g_dst, ws);
    // 3. deg -> norm in place
    k_norm<<<(A_AGG_CELL + 255) / 256, 256, 0, stream>>>(ws, A_AGG_CELL);
    // 4. aggregate gene -> cell
    k_agg<<<(NEDGE + 3) / 4, 256, 0, stream>>>((const float4*)gene_emb, g2c_src, g2c_dst,
                                               ws + A_DEG_G_OUT, ws + A_AGG_CELL);
    // 5. aggregate cell -> gene
    k_agg<<<(NEDGE + 3) / 4, 256, 0, stream>>>((const float4*)cell_emb, c2g_src, c2g_dst,
                                               ws + A_DEG_C_OUT, ws + A_AGG_GENE);
    // 6. h_cell = relu((agg_cell * norm_c_in) @ W_g2c + b_g2c)
    {
        dim3 grid(D / 64, (N_CELL + 63) / 64);
        k_gemm_relu<<<grid, 256, 0, stream>>>(ws + A_AGG_CELL, ws + A_DEG_C_IN,
                                              W_g2c, b_g2c, out_hcell, N_CELL);
    }
    // 7. h_gene = relu((agg_gene * norm_g_in) @ W_c2g + b_c2g)
    {
        dim3 grid(D / 64, (N_GENE + 63) / 64);
        k_gemm_relu<<<grid, 256, 0, stream>>>(ws + A_AGG_GENE, ws + A_DEG_G_IN,
                                              W_c2g, b_c2g, out_hgene, N_GENE);
    }
    // 8. sg[g] = h_gene[g,:] . Wp[0:256];  sc[c] = h_cell[c,:] . Wp[256:512]
    k_rowdot<<<(N_GENE + 3) / 4, 256, 0, stream>>>(out_hgene, Wp, ws + A_SG, N_GENE);
    k_rowdot<<<(N_CELL + 3) / 4, 256, 0, stream>>>(out_hcell, Wp + D, ws + A_SC, N_CELL);
    // 9. score[e] = sg[dec_src[e]] + sc[dec_dst[e]] + bp
    k_score<<<(NEDGE + 255) / 256, 256, 0, stream>>>(dec_src, dec_dst,
                                                     ws + A_SG, ws + A_SC, bp, out_score);
}

// Round 2
// 343.788 us; speedup vs baseline: 4.7087x; 4.7087x over previous
//
#include <hip/hip_runtime.h>

#define N_GENE 4762
#define N_CELL 847
#define NEDGE  200000
#define D      256

// ---- workspace layout (4-byte slots; ints and floats mixed) ----
// deg arrays double as scatter cursors after k_norm zeroes them.
#define A_DEG_G_OUT 0                          // int[4762]  g2c_src histogram (genes)
#define A_DEG_C_IN  (A_DEG_G_OUT + N_GENE)     // int[847]   g2c_dst histogram (cells) -> cursor
#define A_DEG_C_OUT (A_DEG_C_IN + N_CELL)      // int[847]   c2g_src histogram (cells)
#define A_DEG_G_IN  (A_DEG_C_OUT + N_CELL)     // int[4762]  c2g_dst histogram (genes) -> cursor
#define N_DEG       (A_DEG_G_IN + N_GENE)      // = 11218
#define A_NRM_G_OUT N_DEG                      // float[4762]
#define A_NRM_C_IN  (A_NRM_G_OUT + N_GENE)     // float[847]
#define A_NRM_C_OUT (A_NRM_C_IN + N_CELL)      // float[847]
#define A_NRM_G_IN  (A_NRM_C_OUT + N_CELL)     // float[4762]
#define A_OFFS_C    (A_NRM_G_IN + N_GENE)      // int[848]   CSR offsets, dst=cells
#define A_OFFS_G    (A_OFFS_C + N_CELL + 1)    // int[4763]  CSR offsets, dst=genes
#define A_SORTED    (A_OFFS_G + N_GENE + 1)    // int[200000] (reused for both directions)
#define A_AGG_CELL  (A_SORTED + NEDGE)         // float[847*256]
#define A_AGG_GENE  (A_AGG_CELL + N_CELL * D)  // float[4762*256]
#define A_SG        (A_AGG_GENE + N_GENE * D)  // float[4762]
#define A_SC        (A_SG + N_GENE)            // float[847]

__global__ void k_zero_int(int* p, int n) {
    int i = blockIdx.x * blockDim.x + threadIdx.x;
    if (i < n) p[i] = 0;
}

__global__ void k_deg(const int* __restrict__ g2c_src, const int* __restrict__ g2c_dst,
                      const int* __restrict__ c2g_src, const int* __restrict__ c2g_dst,
                      int* __restrict__ deg) {
    int i = blockIdx.x * blockDim.x + threadIdx.x;
    if (i < NEDGE) {
        atomicAdd(&deg[A_DEG_G_OUT + g2c_src[i]], 1);
        atomicAdd(&deg[A_DEG_C_IN  + g2c_dst[i]], 1);
        atomicAdd(&deg[A_DEG_C_OUT + c2g_src[i]], 1);
        atomicAdd(&deg[A_DEG_G_IN  + c2g_dst[i]], 1);
    }
}

// exclusive prefix sum over deg[0..n) -> offs[0..n]; single block of 1024
__global__ __launch_bounds__(1024) void k_scan(const int* __restrict__ deg,
                                               int* __restrict__ offs, int n) {
    __shared__ int tmp[1024];
    __shared__ int carry_s;
    int tid = threadIdx.x;
    if (tid == 0) carry_s = 0;
    __syncthreads();
    for (int base = 0; base < n; base += 1024) {
        int i = base + tid;
        int v = (i < n) ? deg[i] : 0;
        tmp[tid] = v;
        __syncthreads();
        #pragma unroll
        for (int o = 1; o < 1024; o <<= 1) {
            int t = (tid >= o) ? tmp[tid - o] : 0;
            __syncthreads();
            tmp[tid] += t;
            __syncthreads();
        }
        int carry = carry_s;
        if (i < n) offs[i] = carry + tmp[tid] - v;  // exclusive
        __syncthreads();
        if (tid == 0) carry_s = carry + tmp[1023];
        __syncthreads();
    }
    if (tid == 0) offs[n] = carry_s;
}

// norm = rsqrt(max(deg,1)); deg := 0 (becomes scatter cursor)
__global__ void k_norm(int* __restrict__ deg, float* __restrict__ nrm, int n) {
    int i = blockIdx.x * blockDim.x + threadIdx.x;
    if (i < n) {
        nrm[i] = rsqrtf(fmaxf((float)deg[i], 1.0f));
        deg[i] = 0;
    }
}

// counting-sort scatter: sorted[offs[dst[e]] + cur[dst[e]]++] = src[e]
__global__ void k_scatter(const int* __restrict__ src, const int* __restrict__ dst,
                          const int* __restrict__ offs, int* __restrict__ cur,
                          int* __restrict__ sorted) {
    int i = blockIdx.x * blockDim.x + threadIdx.x;
    if (i < NEDGE) {
        int d = dst[i];
        int pos = offs[d] + atomicAdd(&cur[d], 1);
        sorted[pos] = src[i];
    }
}

// one block per dst node; thread t owns column t.
// agg[d,c] = norm_dst[d] * sum_{edges e->d} norm_src[s_e] * emb[s_e, c]
__global__ __launch_bounds__(256) void k_agg_csr(
        const float* __restrict__ emb, const int* __restrict__ sorted,
        const int* __restrict__ offs, const float* __restrict__ norm_src,
        const float* __restrict__ norm_dst, float* __restrict__ agg) {
    int d = blockIdx.x;
    int col = threadIdx.x;
    int e0 = offs[d], e1 = offs[d + 1];
    __shared__ int   sidx[256];
    __shared__ float snrm[256];
    float a0 = 0.f, a1 = 0.f, a2 = 0.f, a3 = 0.f;
    for (int base = e0; base < e1; base += 256) {
        int n = min(256, e1 - base);
        __syncthreads();
        if (col < n) {
            int s = sorted[base + col];
            sidx[col] = s;
            snrm[col] = norm_src[s];
        }
        __syncthreads();
        int i = 0;
        for (; i + 4 <= n; i += 4) {
            a0 += snrm[i + 0] * emb[sidx[i + 0] * D + col];
            a1 += snrm[i + 1] * emb[sidx[i + 1] * D + col];
            a2 += snrm[i + 2] * emb[sidx[i + 2] * D + col];
            a3 += snrm[i + 3] * emb[sidx[i + 3] * D + col];
        }
        for (; i < n; i++) a0 += snrm[i] * emb[sidx[i] * D + col];
    }
    agg[d * D + col] = ((a0 + a1) + (a2 + a3)) * norm_dst[d];
}

// H = relu(X @ W + b), X:[M,256] (already fully normalized), W:[256,256]
__global__ __launch_bounds__(256) void k_gemm_relu(
        const float* __restrict__ X, const float* __restrict__ W,
        const float* __restrict__ b, float* __restrict__ H, int M) {
    const int BM = 64, BN = 64, BK = 32;
    __shared__ float As[BK][BM + 1];
    __shared__ float Bs[BK][BN];
    int bm = blockIdx.y * BM, bn = blockIdx.x * BN;
    int t = threadIdx.x;
    int tx = t & 15, ty = t >> 4;
    float acc[4][4] = {};
    for (int k0 = 0; k0 < D; k0 += BK) {
        {
            int m = t >> 3;
            int k4 = (t & 7) * 4;
            #pragma unroll
            for (int mm = 0; mm < BM; mm += 32) {
                int row = bm + m + mm;
                float4 v = make_float4(0.f, 0.f, 0.f, 0.f);
                if (row < M) v = *(const float4*)&X[row * D + k0 + k4];
                As[k4 + 0][m + mm] = v.x;
                As[k4 + 1][m + mm] = v.y;
                As[k4 + 2][m + mm] = v.z;
                As[k4 + 3][m + mm] = v.w;
            }
        }
        {
            int k = t >> 4;
            int c4 = (t & 15) * 4;
            #pragma unroll
            for (int kk = 0; kk < BK; kk += 16) {
                *(float4*)&Bs[k + kk][c4] = *(const float4*)&W[(k0 + k + kk) * D + bn + c4];
            }
        }
        __syncthreads();
        #pragma unroll
        for (int k = 0; k < BK; k++) {
            float ra[4], rb[4];
            #pragma unroll
            for (int i = 0; i < 4; i++) ra[i] = As[k][ty * 4 + i];
            #pragma unroll
            for (int j = 0; j < 4; j++) rb[j] = Bs[k][tx * 4 + j];
            #pragma unroll
            for (int i = 0; i < 4; i++)
                #pragma unroll
                for (int j = 0; j < 4; j++) acc[i][j] += ra[i] * rb[j];
        }
        __syncthreads();
    }
    #pragma unroll
    for (int i = 0; i < 4; i++) {
        int row = bm + ty * 4 + i;
        if (row < M) {
            #pragma unroll
            for (int j = 0; j < 4; j++) {
                int col = bn + tx * 4 + j;
                H[row * D + col] = fmaxf(acc[i][j] + b[col], 0.0f);
            }
        }
    }
}

// out[r] = dot(H[r,:], wp[0:256]) — one wave per row
__global__ void k_rowdot(const float* __restrict__ H, const float* __restrict__ wp,
                         float* __restrict__ out, int M) {
    int r = blockIdx.x * (blockDim.x >> 6) + (threadIdx.x >> 6);
    int lane = threadIdx.x & 63;
    if (r < M) {
        float4 h = *(const float4*)&H[r * D + lane * 4];
        float4 w = *(const float4*)&wp[lane * 4];
        float s = h.x * w.x + h.y * w.y + h.z * w.z + h.w * w.w;
        #pragma unroll
        for (int o = 32; o > 0; o >>= 1) s += __shfl_down(s, o);
        if (lane == 0) out[r] = s;
    }
}

__global__ void k_score(const int* __restrict__ dsrc, const int* __restrict__ ddst,
                        const float* __restrict__ sg, const float* __restrict__ sc,
                        const float* __restrict__ bp, float* __restrict__ out) {
    int i = blockIdx.x * blockDim.x + threadIdx.x;
    if (i < NEDGE) out[i] = sg[dsrc[i]] + sc[ddst[i]] + bp[0];
}

extern "C" void kernel_launch(void* const* d_in, const int* in_sizes, int n_in,
                              void* d_out, int out_size, void* d_ws, size_t ws_size,
                              hipStream_t stream) {
    const float* gene_emb = (const float*)d_in[0];
    const float* cell_emb = (const float*)d_in[1];
    const float* W_g2c    = (const float*)d_in[2];
    const float* b_g2c    = (const float*)d_in[3];
    const float* W_c2g    = (const float*)d_in[4];
    const float* b_c2g    = (const float*)d_in[5];
    const float* Wp       = (const float*)d_in[6];
    const float* bp       = (const float*)d_in[7];
    const int* g2c_src = (const int*)d_in[8];
    const int* g2c_dst = (const int*)d_in[9];
    const int* c2g_src = (const int*)d_in[10];
    const int* c2g_dst = (const int*)d_in[11];
    const int* dec_src = (const int*)d_in[12];
    const int* dec_dst = (const int*)d_in[13];

    int*   wsi = (int*)d_ws;
    float* wsf = (float*)d_ws;
    float* out = (float*)d_out;
    float* out_score = out;                      // [200000]
    float* out_hgene = out + NEDGE;              // [4762*256]
    float* out_hcell = out + NEDGE + N_GENE * D; // [847*256]

    // 1. zero degree histograms
    k_zero_int<<<(N_DEG + 255) / 256, 256, 0, stream>>>(wsi + A_DEG_G_OUT, N_DEG);
    // 2. degrees (int histograms)
    k_deg<<<(NEDGE + 255) / 256, 256, 0, stream>>>(g2c_src, g2c_dst, c2g_src, c2g_dst,
                                                   wsi + A_DEG_G_OUT);
    // 3. CSR offsets from in-degrees (before deg arrays become cursors)
    k_scan<<<1, 1024, 0, stream>>>(wsi + A_DEG_C_IN, wsi + A_OFFS_C, N_CELL);
    k_scan<<<1, 1024, 0, stream>>>(wsi + A_DEG_G_IN, wsi + A_OFFS_G, N_GENE);
    // 4. deg -> norm; zero deg (cursors)
    k_norm<<<(N_DEG + 255) / 256, 256, 0, stream>>>(wsi + A_DEG_G_OUT,
                                                    wsf + A_NRM_G_OUT, N_DEG);
    // ---- direction 1: gene -> cell ----
    k_scatter<<<(NEDGE + 255) / 256, 256, 0, stream>>>(g2c_src, g2c_dst, wsi + A_OFFS_C,
                                                       wsi + A_DEG_C_IN, wsi + A_SORTED);
    k_agg_csr<<<N_CELL, 256, 0, stream>>>(gene_emb, wsi + A_SORTED, wsi + A_OFFS_C,
                                          wsf + A_NRM_G_OUT, wsf + A_NRM_C_IN,
                                          wsf + A_AGG_CELL);
    {
        dim3 grid(D / 64, (N_CELL + 63) / 64);
        k_gemm_relu<<<grid, 256, 0, stream>>>(wsf + A_AGG_CELL, W_g2c, b_g2c,
                                              out_hcell, N_CELL);
    }
    // ---- direction 2: cell -> gene (reuses sorted buffer) ----
    k_scatter<<<(NEDGE + 255) / 256, 256, 0, stream>>>(c2g_src, c2g_dst, wsi + A_OFFS_G,
                                                       wsi + A_DEG_G_IN, wsi + A_SORTED);
    k_agg_csr<<<N_GENE, 256, 0, stream>>>(cell_emb, wsi + A_SORTED, wsi + A_OFFS_G,
                                          wsf + A_NRM_C_OUT, wsf + A_NRM_G_IN,
                                          wsf + A_AGG_GENE);
    {
        dim3 grid(D / 64, (N_GENE + 63) / 64);
        k_gemm_relu<<<grid, 256, 0, stream>>>(wsf + A_AGG_GENE, W_c2g, b_c2g,
                                              out_hgene, N_GENE);
    }
    // ---- predictor ----
    k_rowdot<<<(N_GENE + 3) / 4, 256, 0, stream>>>(out_hgene, Wp, wsf + A_SG, N_GENE);
    k_rowdot<<<(N_CELL + 3) / 4, 256, 0, stream>>>(out_hcell, Wp + D, wsf + A_SC, N_CELL);
    k_score<<<(NEDGE + 255) / 256, 256, 0, stream>>>(dec_src, dec_dst,
                                                     wsf + A_SG, wsf + A_SC, bp, out_score);
}

// Round 3
// 252.193 us; speedup vs baseline: 6.4189x; 1.3632x over previous
//
#include <hip/hip_runtime.h>

#define N_GENE 4762
#define N_CELL 847
#define NEDGE  200000
#define D      256

// ---- histogram segment layout (bins, concatenated) ----
#define S_G_OUT 0                      // [4762] g2c_src degrees (genes)
#define S_C_IN  (S_G_OUT + N_GENE)     // [847]  g2c_dst degrees (cells)
#define S_C_OUT (S_C_IN + N_CELL)      // [847]  c2g_src degrees (cells)
#define S_G_IN  (S_C_OUT + N_CELL)     // [4762] c2g_dst degrees (genes)
#define NBINS   (S_G_IN + N_GENE)      // 11218

// ---- workspace layout (4-byte slots) ----
#define A_DEG      0                      // int[11218], reused as scatter cursors
#define A_NRM      NBINS                  // float[11218]
#define A_OFFS_C   (A_NRM + NBINS)        // int[848]
#define A_OFFS_G   (A_OFFS_C + N_CELL+1)  // int[4763]
#define A_SORTED   (A_OFFS_G + N_GENE+1)  // int[200000] (reused for both dirs)
#define A_AGG_CELL (A_SORTED + NEDGE)     // float[847*256]
#define A_AGG_GENE (A_AGG_CELL + N_CELL*D)// float[4762*256]
#define A_SG       (A_AGG_GENE + N_GENE*D)// float[4762]
#define A_SC       (A_SG + N_GENE)        // float[847]

__global__ void k_zero_int(int* p, int n) {
    int i = blockIdx.x * blockDim.x + threadIdx.x;
    if (i < n) p[i] = 0;
}

// Per-block LDS histograms of all 4 index arrays, merged with one global
// atomicAdd per nonzero bin (low, spread contention).
__global__ __launch_bounds__(256) void k_hist(
        const int* __restrict__ g2c_src, const int* __restrict__ g2c_dst,
        const int* __restrict__ c2g_src, const int* __restrict__ c2g_dst,
        int* __restrict__ deg) {
    __shared__ int sh[NBINS];
    int tid = threadIdx.x;
    for (int j = tid; j < NBINS; j += 256) sh[j] = 0;
    __syncthreads();
    int chunk = (NEDGE + gridDim.x - 1) / gridDim.x;
    int e0 = blockIdx.x * chunk, e1 = min(NEDGE, e0 + chunk);
    for (int e = e0 + tid; e < e1; e += 256) {
        atomicAdd(&sh[S_G_OUT + g2c_src[e]], 1);
        atomicAdd(&sh[S_C_IN  + g2c_dst[e]], 1);
        atomicAdd(&sh[S_C_OUT + c2g_src[e]], 1);
        atomicAdd(&sh[S_G_IN  + c2g_dst[e]], 1);
    }
    __syncthreads();
    for (int j = tid; j < NBINS; j += 256) {
        int h = sh[j];
        if (h) atomicAdd(&deg[j], h);
    }
}

// Exclusive scan; block 0: cells (n=847), block 1: genes (n=4762).
__global__ __launch_bounds__(1024) void k_scan2(
        const int* __restrict__ degC, int* __restrict__ offsC,
        const int* __restrict__ degG, int* __restrict__ offsG) {
    const int* src = (blockIdx.x == 0) ? degC : degG;
    int* dst       = (blockIdx.x == 0) ? offsC : offsG;
    int n          = (blockIdx.x == 0) ? N_CELL : N_GENE;
    int tid = threadIdx.x;
    int per = (n + 1023) >> 10;          // <=5
    int base = tid * per;
    int v[8];
    int s = 0;
    for (int i = 0; i < per; i++) {
        int x = (base + i < n) ? src[base + i] : 0;
        v[i] = s;                         // local exclusive prefix
        s += x;
    }
    int lane = tid & 63, w = tid >> 6;    // 16 waves
    int t = s;                            // inclusive wave scan
    #pragma unroll
    for (int off = 1; off < 64; off <<= 1) {
        int u = __shfl_up(t, off);
        if (lane >= off) t += u;
    }
    __shared__ int wsum[16];
    if (lane == 63) wsum[w] = t;
    __syncthreads();
    if (w == 0 && lane < 16) {
        int x = wsum[lane];
        #pragma unroll
        for (int off = 1; off < 16; off <<= 1) {
            int u = __shfl_up(x, off);
            if (lane >= off) x += u;
        }
        wsum[lane] = x;                   // inclusive wave totals
    }
    __syncthreads();
    int wbase = (w == 0) ? 0 : wsum[w - 1];
    int excl = wbase + t - s;             // block-exclusive prefix for this thread
    for (int i = 0; i < per; i++)
        if (base + i < n) dst[base + i] = excl + v[i];
    if (tid == 1023) dst[n] = excl + s;   // grand total
}

// norm = rsqrt(max(deg,1)); deg := 0 (becomes scatter cursor)
__global__ void k_norm(int* __restrict__ deg, float* __restrict__ nrm, int n) {
    int i = blockIdx.x * blockDim.x + threadIdx.x;
    if (i < n) {
        nrm[i] = rsqrtf(fmaxf((float)deg[i], 1.0f));
        deg[i] = 0;
    }
}

// Two-pass block counting sort: LDS-hist chunk, reserve contiguous range per
// nonzero bin with ONE global atomic, then place edges via LDS cursors.
__global__ __launch_bounds__(256) void k_scatter_blk(
        const int* __restrict__ src, const int* __restrict__ dst,
        const int* __restrict__ offs, int* __restrict__ gcur,
        int* __restrict__ sorted, int nbins) {
    __shared__ int sh[N_GENE];  // max bins
    int tid = threadIdx.x;
    for (int j = tid; j < nbins; j += 256) sh[j] = 0;
    __syncthreads();
    int chunk = (NEDGE + gridDim.x - 1) / gridDim.x;
    int e0 = blockIdx.x * chunk, e1 = min(NEDGE, e0 + chunk);
    for (int e = e0 + tid; e < e1; e += 256) atomicAdd(&sh[dst[e]], 1);
    __syncthreads();
    for (int j = tid; j < nbins; j += 256) {
        int h = sh[j];
        sh[j] = h ? atomicAdd(&gcur[j], h) : 0;   // sh[j] := my block's start rank
    }
    __syncthreads();
    for (int e = e0 + tid; e < e1; e += 256) {
        int d = dst[e];
        int r = atomicAdd(&sh[d], 1);
        sorted[offs[d] + r] = src[e];
    }
}

// One wave per dst node; lane owns 4 columns (float4).
// agg[d,:] = norm_dst[d] * sum_e norm_src[s_e] * emb[s_e,:]
__global__ __launch_bounds__(64) void k_agg4(
        const float4* __restrict__ emb4, const int* __restrict__ sorted,
        const int* __restrict__ offs, const float* __restrict__ nrm_src,
        const float* __restrict__ nrm_dst, float4* __restrict__ agg4) {
    int d = blockIdx.x, lane = threadIdx.x;
    int e0 = offs[d], e1 = offs[d + 1];
    __shared__ int   sidx[64];
    __shared__ float snrm[64];
    float ax = 0.f, ay = 0.f, az = 0.f, aw = 0.f;
    for (int base = e0; base < e1; base += 64) {
        int n = min(64, e1 - base);
        __syncthreads();
        if (lane < n) {
            int s = sorted[base + lane];
            sidx[lane] = s;
            snrm[lane] = nrm_src[s];
        }
        __syncthreads();
        int i = 0;
        for (; i + 4 <= n; i += 4) {
            float4 v0 = emb4[sidx[i + 0] * (D / 4) + lane]; float n0 = snrm[i + 0];
            float4 v1 = emb4[sidx[i + 1] * (D / 4) + lane]; float n1 = snrm[i + 1];
            float4 v2 = emb4[sidx[i + 2] * (D / 4) + lane]; float n2 = snrm[i + 2];
            float4 v3 = emb4[sidx[i + 3] * (D / 4) + lane]; float n3 = snrm[i + 3];
            ax += v0.x * n0 + v1.x * n1 + v2.x * n2 + v3.x * n3;
            ay += v0.y * n0 + v1.y * n1 + v2.y * n2 + v3.y * n3;
            az += v0.z * n0 + v1.z * n1 + v2.z * n2 + v3.z * n3;
            aw += v0.w * n0 + v1.w * n1 + v2.w * n2 + v3.w * n3;
        }
        for (; i < n; i++) {
            float4 v = emb4[sidx[i] * (D / 4) + lane]; float nn = snrm[i];
            ax += v.x * nn; ay += v.y * nn; az += v.z * nn; aw += v.w * nn;
        }
    }
    float nd = nrm_dst[d];
    agg4[d * (D / 4) + lane] = make_float4(ax * nd, ay * nd, az * nd, aw * nd);
}

// H = relu(X @ W + b), X:[M,256] (already fully normalized), W:[256,256]
__global__ __launch_bounds__(256) void k_gemm_relu(
        const float* __restrict__ X, const float* __restrict__ W,
        const float* __restrict__ b, float* __restrict__ H, int M) {
    const int BM = 64, BN = 64, BK = 32;
    __shared__ float As[BK][BM + 1];
    __shared__ float Bs[BK][BN];
    int bm = blockIdx.y * BM, bn = blockIdx.x * BN;
    int t = threadIdx.x;
    int tx = t & 15, ty = t >> 4;
    float acc[4][4] = {};
    for (int k0 = 0; k0 < D; k0 += BK) {
        {
            int m = t >> 3;
            int k4 = (t & 7) * 4;
            #pragma unroll
            for (int mm = 0; mm < BM; mm += 32) {
                int row = bm + m + mm;
                float4 v = make_float4(0.f, 0.f, 0.f, 0.f);
                if (row < M) v = *(const float4*)&X[row * D + k0 + k4];
                As[k4 + 0][m + mm] = v.x;
                As[k4 + 1][m + mm] = v.y;
                As[k4 + 2][m + mm] = v.z;
                As[k4 + 3][m + mm] = v.w;
            }
        }
        {
            int k = t >> 4;
            int c4 = (t & 15) * 4;
            #pragma unroll
            for (int kk = 0; kk < BK; kk += 16) {
                *(float4*)&Bs[k + kk][c4] = *(const float4*)&W[(k0 + k + kk) * D + bn + c4];
            }
        }
        __syncthreads();
        #pragma unroll
        for (int k = 0; k < BK; k++) {
            float ra[4], rb[4];
            #pragma unroll
            for (int i = 0; i < 4; i++) ra[i] = As[k][ty * 4 + i];
            #pragma unroll
            for (int j = 0; j < 4; j++) rb[j] = Bs[k][tx * 4 + j];
            #pragma unroll
            for (int i = 0; i < 4; i++)
                #pragma unroll
                for (int j = 0; j < 4; j++) acc[i][j] += ra[i] * rb[j];
        }
        __syncthreads();
    }
    #pragma unroll
    for (int i = 0; i < 4; i++) {
        int row = bm + ty * 4 + i;
        if (row < M) {
            #pragma unroll
            for (int j = 0; j < 4; j++) {
                int col = bn + tx * 4 + j;
                H[row * D + col] = fmaxf(acc[i][j] + b[col], 0.0f);
            }
        }
    }
}

// out[r] = dot(H[r,:], wp[0:256]) — one wave per row
__global__ void k_rowdot(const float* __restrict__ H, const float* __restrict__ wp,
                         float* __restrict__ out, int M) {
    int r = blockIdx.x * (blockDim.x >> 6) + (threadIdx.x >> 6);
    int lane = threadIdx.x & 63;
    if (r < M) {
        float4 h = *(const float4*)&H[r * D + lane * 4];
        float4 w = *(const float4*)&wp[lane * 4];
        float s = h.x * w.x + h.y * w.y + h.z * w.z + h.w * w.w;
        #pragma unroll
        for (int o = 32; o > 0; o >>= 1) s += __shfl_down(s, o);
        if (lane == 0) out[r] = s;
    }
}

__global__ void k_score(const int* __restrict__ dsrc, const int* __restrict__ ddst,
                        const float* __restrict__ sg, const float* __restrict__ sc,
                        const float* __restrict__ bp, float* __restrict__ out) {
    int i = blockIdx.x * blockDim.x + threadIdx.x;
    if (i < NEDGE) out[i] = sg[dsrc[i]] + sc[ddst[i]] + bp[0];
}

extern "C" void kernel_launch(void* const* d_in, const int* in_sizes, int n_in,
                              void* d_out, int out_size, void* d_ws, size_t ws_size,
                              hipStream_t stream) {
    const float* gene_emb = (const float*)d_in[0];
    const float* cell_emb = (const float*)d_in[1];
    const float* W_g2c    = (const float*)d_in[2];
    const float* b_g2c    = (const float*)d_in[3];
    const float* W_c2g    = (const float*)d_in[4];
    const float* b_c2g    = (const float*)d_in[5];
    const float* Wp       = (const float*)d_in[6];
    const float* bp       = (const float*)d_in[7];
    const int* g2c_src = (const int*)d_in[8];
    const int* g2c_dst = (const int*)d_in[9];
    const int* c2g_src = (const int*)d_in[10];
    const int* c2g_dst = (const int*)d_in[11];
    const int* dec_src = (const int*)d_in[12];
    const int* dec_dst = (const int*)d_in[13];

    int*   wsi = (int*)d_ws;
    float* wsf = (float*)d_ws;
    float* out = (float*)d_out;
    float* out_score = out;                      // [200000]
    float* out_hgene = out + NEDGE;              // [4762*256]
    float* out_hcell = out + NEDGE + N_GENE * D; // [847*256]

    // 1. zero degree bins
    k_zero_int<<<(NBINS + 255) / 256, 256, 0, stream>>>(wsi + A_DEG, NBINS);
    // 2. degrees via per-block LDS histograms
    k_hist<<<32, 256, 0, stream>>>(g2c_src, g2c_dst, c2g_src, c2g_dst, wsi + A_DEG);
    // 3. CSR offsets (both dst arrays, one launch, before deg becomes cursors)
    k_scan2<<<2, 1024, 0, stream>>>(wsi + A_DEG + S_C_IN, wsi + A_OFFS_C,
                                    wsi + A_DEG + S_G_IN, wsi + A_OFFS_G);
    // 4. deg -> norm; zero deg (cursors)
    k_norm<<<(NBINS + 255) / 256, 256, 0, stream>>>(wsi + A_DEG, wsf + A_NRM, NBINS);
    // ---- direction 1: gene -> cell ----
    k_scatter_blk<<<64, 256, 0, stream>>>(g2c_src, g2c_dst, wsi + A_OFFS_C,
                                          wsi + A_DEG + S_C_IN, wsi + A_SORTED, N_CELL);
    k_agg4<<<N_CELL, 64, 0, stream>>>((const float4*)gene_emb, wsi + A_SORTED,
                                      wsi + A_OFFS_C, wsf + A_NRM + S_G_OUT,
                                      wsf + A_NRM + S_C_IN, (float4*)(wsf + A_AGG_CELL));
    {
        dim3 grid(D / 64, (N_CELL + 63) / 64);
        k_gemm_relu<<<grid, 256, 0, stream>>>(wsf + A_AGG_CELL, W_g2c, b_g2c,
                                              out_hcell, N_CELL);
    }
    // ---- direction 2: cell -> gene (reuses sorted buffer) ----
    k_scatter_blk<<<64, 256, 0, stream>>>(c2g_src, c2g_dst, wsi + A_OFFS_G,
                                          wsi + A_DEG + S_G_IN, wsi + A_SORTED, N_GENE);
    k_agg4<<<N_GENE, 64, 0, stream>>>((const float4*)cell_emb, wsi + A_SORTED,
                                      wsi + A_OFFS_G, wsf + A_NRM + S_C_OUT,
                                      wsf + A_NRM + S_G_IN, (float4*)(wsf + A_AGG_GENE));
    {
        dim3 grid(D / 64, (N_GENE + 63) / 64);
        k_gemm_relu<<<grid, 256, 0, stream>>>(wsf + A_AGG_GENE, W_c2g, b_c2g,
                                              out_hgene, N_GENE);
    }
    // ---- predictor ----
    k_rowdot<<<(N_GENE + 3) / 4, 256, 0, stream>>>(out_hgene, Wp, wsf + A_SG, N_GENE);
    k_rowdot<<<(N_CELL + 3) / 4, 256, 0, stream>>>(out_hcell, Wp + D, wsf + A_SC, N_CELL);
    k_score<<<(NEDGE + 255) / 256, 256, 0, stream>>>(dec_src, dec_dst,
                                                     wsf + A_SG, wsf + A_SC, bp, out_score);
}

// Round 4
// 176.440 us; speedup vs baseline: 9.1747x; 1.4293x over previous
//
#include <hip/hip_runtime.h>

#define N_GENE 4762
#define N_CELL 847
#define NEDGE  200000
#define D      256
#define NPART  64     // partial-histogram blocks (also scatter blocks)

// ---- histogram segment layout (bins, concatenated) ----
#define S_G_OUT 0                      // [4762] g2c_src degrees (genes)
#define S_C_IN  (S_G_OUT + N_GENE)     // [847]  g2c_dst degrees (cells)
#define S_C_OUT (S_C_IN + N_CELL)      // [847]  c2g_src degrees (cells)
#define S_G_IN  (S_C_OUT + N_CELL)     // [4762] c2g_dst degrees (genes)
#define NBINS   (S_G_IN + N_GENE)      // 11218

// ---- workspace layout (4-byte slots) ----
#define A_DEG      0                        // int[11218]
#define A_NRM      NBINS                    // float[11218]
#define A_OFFS_C   (A_NRM + NBINS)          // int[848]
#define A_OFFS_G   (A_OFFS_C + N_CELL + 1)  // int[4763]
#define A_SORT_C   (A_OFFS_G + N_GENE + 1)  // int[200000]
#define A_SORT_G   (A_SORT_C + NEDGE)       // int[200000]
#define A_PART     (A_SORT_G + NEDGE)       // int[64*11218]
#define A_AGG_CELL (A_PART + NPART * NBINS) // float[847*256]
#define A_AGG_GENE (A_AGG_CELL + N_CELL*D)  // float[4762*256]
#define A_SG       (A_AGG_GENE + N_GENE*D)  // float[4762]
#define A_SC       (A_SG + N_GENE)          // float[847]

// Per-block LDS histograms of all 4 index arrays -> partial[b][j].
// No global atomics; plain coalesced stores.
__global__ __launch_bounds__(1024) void k_hist_part(
        const int* __restrict__ g2c_src, const int* __restrict__ g2c_dst,
        const int* __restrict__ c2g_src, const int* __restrict__ c2g_dst,
        int* __restrict__ partial) {
    __shared__ int sh[NBINS];
    int tid = threadIdx.x;
    for (int j = tid; j < NBINS; j += 1024) sh[j] = 0;
    __syncthreads();
    const int chunk = (NEDGE + NPART - 1) / NPART;
    int e0 = blockIdx.x * chunk, e1 = min(NEDGE, e0 + chunk);
    for (int e = e0 + tid; e < e1; e += 1024) {
        atomicAdd(&sh[S_G_OUT + g2c_src[e]], 1);
        atomicAdd(&sh[S_C_IN  + g2c_dst[e]], 1);
        atomicAdd(&sh[S_C_OUT + c2g_src[e]], 1);
        atomicAdd(&sh[S_G_IN  + c2g_dst[e]], 1);
    }
    __syncthreads();
    int* p = partial + blockIdx.x * NBINS;
    for (int j = tid; j < NBINS; j += 1024) p[j] = sh[j];
}

// deg[j] = sum_b partial[b][j]; partial[b][j] := exclusive prefix over b
// (per-block base ranks for the deterministic counting sort);
// nrm[j] = rsqrt(max(deg,1)).
__global__ void k_hist_reduce(int* __restrict__ partial, int* __restrict__ deg,
                              float* __restrict__ nrm) {
    int j = blockIdx.x * blockDim.x + threadIdx.x;
    if (j < NBINS) {
        int s = 0;
        #pragma unroll 4
        for (int b = 0; b < NPART; b++) {
            int t = partial[b * NBINS + j];
            partial[b * NBINS + j] = s;
            s += t;
        }
        deg[j] = s;
        nrm[j] = rsqrtf(fmaxf((float)s, 1.0f));
    }
}

// Exclusive scan; block 0: cells (n=847), block 1: genes (n=4762).
__global__ __launch_bounds__(1024) void k_scan2(
        const int* __restrict__ degC, int* __restrict__ offsC,
        const int* __restrict__ degG, int* __restrict__ offsG) {
    const int* src = (blockIdx.x == 0) ? degC : degG;
    int* dst       = (blockIdx.x == 0) ? offsC : offsG;
    int n          = (blockIdx.x == 0) ? N_CELL : N_GENE;
    int tid = threadIdx.x;
    int per = (n + 1023) >> 10;
    int base = tid * per;
    int v[8];
    int s = 0;
    for (int i = 0; i < per; i++) {
        int x = (base + i < n) ? src[base + i] : 0;
        v[i] = s;
        s += x;
    }
    int lane = tid & 63, w = tid >> 6;
    int t = s;
    #pragma unroll
    for (int off = 1; off < 64; off <<= 1) {
        int u = __shfl_up(t, off);
        if (lane >= off) t += u;
    }
    __shared__ int wsum[16];
    if (lane == 63) wsum[w] = t;
    __syncthreads();
    if (w == 0 && lane < 16) {
        int x = wsum[lane];
        #pragma unroll
        for (int off = 1; off < 16; off <<= 1) {
            int u = __shfl_up(x, off);
            if (lane >= off) x += u;
        }
        wsum[lane] = x;
    }
    __syncthreads();
    int wbase = (w == 0) ? 0 : wsum[w - 1];
    int excl = wbase + t - s;
    for (int i = 0; i < per; i++)
        if (base + i < n) dst[base + i] = excl + v[i];
    if (tid == 1023) dst[n] = excl + s;
}

// Deterministic counting sort, zero global atomics: LDS cursors seeded with
// this block's exclusive base ranks from partial[]. grid=(NPART, 2).
__global__ __launch_bounds__(1024) void k_scatter2(
        const int* __restrict__ g2c_src, const int* __restrict__ g2c_dst,
        const int* __restrict__ c2g_src, const int* __restrict__ c2g_dst,
        const int* __restrict__ partial,
        const int* __restrict__ offsC, const int* __restrict__ offsG,
        int* __restrict__ sortC, int* __restrict__ sortG) {
    __shared__ int sh[N_GENE];
    int tid = threadIdx.x;
    int dir = blockIdx.y;
    const int* src  = dir ? c2g_src : g2c_src;
    const int* dst  = dir ? c2g_dst : g2c_dst;
    const int* offs = dir ? offsG : offsC;
    int* sorted     = dir ? sortG : sortC;
    int seg         = dir ? S_G_IN : S_C_IN;
    int nb          = dir ? N_GENE : N_CELL;
    const int* base = partial + blockIdx.x * NBINS + seg;
    for (int j = tid; j < nb; j += 1024) sh[j] = base[j];
    __syncthreads();
    const int chunk = (NEDGE + NPART - 1) / NPART;
    int e0 = blockIdx.x * chunk, e1 = min(NEDGE, e0 + chunk);
    for (int e = e0 + tid; e < e1; e += 1024) {
        int d = dst[e];
        int r = atomicAdd(&sh[d], 1);
        sorted[offs[d] + r] = src[e];
    }
}

// Both directions fused; one wave per dst node (4 waves/block), lane owns 4
// columns. agg[d,:] = nrm_dst[d] * sum_e nrm_src[s_e] * emb[s_e,:]
__global__ __launch_bounds__(256) void k_agg2(
        const float4* __restrict__ gene4, const float4* __restrict__ cell4,
        const int* __restrict__ sortC, const int* __restrict__ sortG,
        const int* __restrict__ offsC, const int* __restrict__ offsG,
        const float* __restrict__ nrm,
        float4* __restrict__ aggC, float4* __restrict__ aggG) {
    int w = threadIdx.x >> 6, lane = threadIdx.x & 63;
    int d = blockIdx.x * 4 + w;
    if (d >= N_CELL + N_GENE) return;
    bool isCell = d < N_CELL;
    int dd = isCell ? d : d - N_CELL;
    const float4* emb    = isCell ? gene4 : cell4;
    const int*    sorted = isCell ? sortC : sortG;
    const int*    offs   = isCell ? offsC : offsG;
    const float*  nsrc   = isCell ? nrm + S_G_OUT : nrm + S_C_OUT;
    float         ndv    = isCell ? nrm[S_C_IN + dd] : nrm[S_G_IN + dd];
    float4*       agg    = isCell ? aggC : aggG;
    int e0 = offs[dd], e1 = offs[dd + 1];
    __shared__ int   sidx[4][64];
    __shared__ float snrm[4][64];
    float ax = 0.f, ay = 0.f, az = 0.f, aw = 0.f;
    for (int base = e0; base < e1; base += 64) {
        int n = min(64, e1 - base);
        if (lane < n) {
            int s = sorted[base + lane];
            sidx[w][lane] = s;
            snrm[w][lane] = nsrc[s];
        }
        // same-wave LDS write->read: program order, no barrier needed
        int i = 0;
        for (; i + 4 <= n; i += 4) {
            float4 v0 = emb[sidx[w][i + 0] * (D / 4) + lane]; float n0 = snrm[w][i + 0];
            float4 v1 = emb[sidx[w][i + 1] * (D / 4) + lane]; float n1 = snrm[w][i + 1];
            float4 v2 = emb[sidx[w][i + 2] * (D / 4) + lane]; float n2 = snrm[w][i + 2];
            float4 v3 = emb[sidx[w][i + 3] * (D / 4) + lane]; float n3 = snrm[w][i + 3];
            ax += v0.x * n0 + v1.x * n1 + v2.x * n2 + v3.x * n3;
            ay += v0.y * n0 + v1.y * n1 + v2.y * n2 + v3.y * n3;
            az += v0.z * n0 + v1.z * n1 + v2.z * n2 + v3.z * n3;
            aw += v0.w * n0 + v1.w * n1 + v2.w * n2 + v3.w * n3;
        }
        for (; i < n; i++) {
            float4 v = emb[sidx[w][i] * (D / 4) + lane]; float nn = snrm[w][i];
            ax += v.x * nn; ay += v.y * nn; az += v.z * nn; aw += v.w * nn;
        }
    }
    agg[dd * (D / 4) + lane] = make_float4(ax * ndv, ay * ndv, az * ndv, aw * ndv);
}

// Both GEMMs fused via blockIdx.z: H = relu(X @ W + b)
__global__ __launch_bounds__(256) void k_gemm2(
        const float* __restrict__ aggC, const float* __restrict__ aggG,
        const float* __restrict__ W_g2c, const float* __restrict__ b_g2c,
        const float* __restrict__ W_c2g, const float* __restrict__ b_c2g,
        float* __restrict__ hC, float* __restrict__ hG) {
    int z = blockIdx.z;
    const float* X = z ? aggG : aggC;
    const float* W = z ? W_c2g : W_g2c;
    const float* bb = z ? b_c2g : b_g2c;
    float* H = z ? hG : hC;
    int M = z ? N_GENE : N_CELL;
    const int BM = 64, BN = 64, BK = 32;
    int bm = blockIdx.y * BM, bn = blockIdx.x * BN;
    if (bm >= M) return;
    __shared__ float As[BK][BM + 1];
    __shared__ float Bs[BK][BN];
    int t = threadIdx.x;
    int tx = t & 15, ty = t >> 4;
    float acc[4][4] = {};
    for (int k0 = 0; k0 < D; k0 += BK) {
        {
            int m = t >> 3;
            int k4 = (t & 7) * 4;
            #pragma unroll
            for (int mm = 0; mm < BM; mm += 32) {
                int row = bm + m + mm;
                float4 v = make_float4(0.f, 0.f, 0.f, 0.f);
                if (row < M) v = *(const float4*)&X[row * D + k0 + k4];
                As[k4 + 0][m + mm] = v.x;
                As[k4 + 1][m + mm] = v.y;
                As[k4 + 2][m + mm] = v.z;
                As[k4 + 3][m + mm] = v.w;
            }
        }
        {
            int k = t >> 4;
            int c4 = (t & 15) * 4;
            #pragma unroll
            for (int kk = 0; kk < BK; kk += 16) {
                *(float4*)&Bs[k + kk][c4] = *(const float4*)&W[(k0 + k + kk) * D + bn + c4];
            }
        }
        __syncthreads();
        #pragma unroll
        for (int k = 0; k < BK; k++) {
            float ra[4], rb[4];
            #pragma unroll
            for (int i = 0; i < 4; i++) ra[i] = As[k][ty * 4 + i];
            #pragma unroll
            for (int j = 0; j < 4; j++) rb[j] = Bs[k][tx * 4 + j];
            #pragma unroll
            for (int i = 0; i < 4; i++)
                #pragma unroll
                for (int j = 0; j < 4; j++) acc[i][j] += ra[i] * rb[j];
        }
        __syncthreads();
    }
    #pragma unroll
    for (int i = 0; i < 4; i++) {
        int row = bm + ty * 4 + i;
        if (row < M) {
            #pragma unroll
            for (int j = 0; j < 4; j++) {
                int col = bn + tx * 4 + j;
                H[row * D + col] = fmaxf(acc[i][j] + bb[col], 0.0f);
            }
        }
    }
}

// sg[g] = h_gene[g,:].Wp[0:256]; sc[c] = h_cell[c,:].Wp[256:512] — one launch
__global__ void k_rowdot2(const float* __restrict__ hG, const float* __restrict__ hC,
                          const float* __restrict__ Wp,
                          float* __restrict__ sg, float* __restrict__ sc) {
    int r = blockIdx.x * (blockDim.x >> 6) + (threadIdx.x >> 6);
    int lane = threadIdx.x & 63;
    if (r >= N_GENE + N_CELL) return;
    bool g = r < N_GENE;
    int rr = g ? r : r - N_GENE;
    const float* H  = g ? hG : hC;
    const float* wp = g ? Wp : Wp + D;
    float* o        = g ? sg : sc;
    float4 h = *(const float4*)&H[rr * D + lane * 4];
    float4 w = *(const float4*)&wp[lane * 4];
    float s = h.x * w.x + h.y * w.y + h.z * w.z + h.w * w.w;
    #pragma unroll
    for (int o2 = 32; o2 > 0; o2 >>= 1) s += __shfl_down(s, o2);
    if (lane == 0) o[rr] = s;
}

__global__ void k_score(const int* __restrict__ dsrc, const int* __restrict__ ddst,
                        const float* __restrict__ sg, const float* __restrict__ sc,
                        const float* __restrict__ bp, float* __restrict__ out) {
    int i = blockIdx.x * blockDim.x + threadIdx.x;
    if (i < NEDGE) out[i] = sg[dsrc[i]] + sc[ddst[i]] + bp[0];
}

extern "C" void kernel_launch(void* const* d_in, const int* in_sizes, int n_in,
                              void* d_out, int out_size, void* d_ws, size_t ws_size,
                              hipStream_t stream) {
    const float* gene_emb = (const float*)d_in[0];
    const float* cell_emb = (const float*)d_in[1];
    const float* W_g2c    = (const float*)d_in[2];
    const float* b_g2c    = (const float*)d_in[3];
    const float* W_c2g    = (const float*)d_in[4];
    const float* b_c2g    = (const float*)d_in[5];
    const float* Wp       = (const float*)d_in[6];
    const float* bp       = (const float*)d_in[7];
    const int* g2c_src = (const int*)d_in[8];
    const int* g2c_dst = (const int*)d_in[9];
    const int* c2g_src = (const int*)d_in[10];
    const int* c2g_dst = (const int*)d_in[11];
    const int* dec_src = (const int*)d_in[12];
    const int* dec_dst = (const int*)d_in[13];

    int*   wsi = (int*)d_ws;
    float* wsf = (float*)d_ws;
    float* out = (float*)d_out;
    float* out_score = out;                      // [200000]
    float* out_hgene = out + NEDGE;              // [4762*256]
    float* out_hcell = out + NEDGE + N_GENE * D; // [847*256]

    // 1. per-block partial histograms (no atomics to global)
    k_hist_part<<<NPART, 1024, 0, stream>>>(g2c_src, g2c_dst, c2g_src, c2g_dst,
                                            wsi + A_PART);
    // 2. reduce partials -> deg, nrm; partial := per-block exclusive base ranks
    k_hist_reduce<<<(NBINS + 255) / 256, 256, 0, stream>>>(wsi + A_PART, wsi + A_DEG,
                                                           wsf + A_NRM);
    // 3. CSR offsets for both dst spaces
    k_scan2<<<2, 1024, 0, stream>>>(wsi + A_DEG + S_C_IN, wsi + A_OFFS_C,
                                    wsi + A_DEG + S_G_IN, wsi + A_OFFS_G);
    // 4. deterministic counting sort, both directions, zero global atomics
    {
        dim3 grid(NPART, 2);
        k_scatter2<<<grid, 1024, 0, stream>>>(g2c_src, g2c_dst, c2g_src, c2g_dst,
                                              wsi + A_PART, wsi + A_OFFS_C,
                                              wsi + A_OFFS_G, wsi + A_SORT_C,
                                              wsi + A_SORT_G);
    }
    // 5. aggregate both directions (wave per dst node)
    k_agg2<<<(N_CELL + N_GENE + 3) / 4, 256, 0, stream>>>(
        (const float4*)gene_emb, (const float4*)cell_emb,
        wsi + A_SORT_C, wsi + A_SORT_G, wsi + A_OFFS_C, wsi + A_OFFS_G,
        wsf + A_NRM, (float4*)(wsf + A_AGG_CELL), (float4*)(wsf + A_AGG_GENE));
    // 6. both GEMMs + bias + relu
    {
        dim3 grid(D / 64, (N_GENE + 63) / 64, 2);
        k_gemm2<<<grid, 256, 0, stream>>>(wsf + A_AGG_CELL, wsf + A_AGG_GENE,
                                          W_g2c, b_g2c, W_c2g, b_c2g,
                                          out_hcell, out_hgene);
    }
    // 7. predictor row dots (both node types)
    k_rowdot2<<<(N_GENE + N_CELL + 3) / 4, 256, 0, stream>>>(out_hgene, out_hcell, Wp,
                                                             wsf + A_SG, wsf + A_SC);
    // 8. edge scores
    k_score<<<(NEDGE + 255) / 256, 256, 0, stream>>>(dec_src, dec_dst,
                                                     wsf + A_SG, wsf + A_SC, bp, out_score);
}